// Round 2
// baseline (65.371 us; speedup 1.0000x reference)
//
#include <hip/hip_runtime.h>

// APLoss (r2d2 QAPLoss): grid-sample warp + pairwise sim + differentiable AP.
// B=2, H=W=32 -> N=M=1024, D=128, 25 bins. Output: single f32 mean AP.
//
// Math trick: with u = 24*(1-sim), cumsum over bins of the triangular
// memberships is exactly clamp(k+1-u, 0, 1)  (k = 0..24, valid for u >= 0;
// sims <= 1 so u >= -eps, error negligible). So we accumulate the CUMULATIVE
// soft counts CN_k = sum_m clamp(...) and CR_k = sum_m lab*clamp(...) directly
// with static loop indices, and recover per-bin rec by differencing.

#define HW32 32
#define C128 128
#define NQBINS 25
#define QT 16      // queries per k_simhist block
#define MT 256     // m-chunk per k_simhist block
#define PSTRIDE 52 // floats per (query, chunk) partial record (16B aligned)

// ---------------- K1: transpose desc1 + bilinear grid-sample desc2 ----------
__global__ __launch_bounds__(128) void k_prep(const float* __restrict__ desc1,
                                              const float* __restrict__ desc2,
                                              const float* __restrict__ grd,
                                              float* __restrict__ qmat,
                                              float* __restrict__ db)
{
    int pos = blockIdx.x;          // b*1024 + m
    int b = pos >> 10;
    int m = pos & 1023;
    int c = threadIdx.x;

    // desc1 (B,C,H*W) -> qmat (B,N,C)
    qmat[(size_t)pos * C128 + c] = desc1[(size_t)(b * C128 + c) * 1024 + m];

    float gx = grd[(size_t)pos * 2 + 0];
    float gy = grd[(size_t)pos * 2 + 1];
    float fx = ((gx + 1.f) * (float)HW32 - 1.f) * 0.5f;
    float fy = ((gy + 1.f) * (float)HW32 - 1.f) * 0.5f;
    float x0f = floorf(fx), y0f = floorf(fy);
    float wx1 = fx - x0f, wy1 = fy - y0f;
    float wx0 = 1.f - wx1, wy0 = 1.f - wy1;
    int x0 = (int)x0f, y0 = (int)y0f;

    const float* base = desc2 + (size_t)(b * C128 + c) * 1024;
    float acc = 0.f;
    if ((unsigned)y0 < HW32 && (unsigned)x0 < HW32)
        acc += wy0 * wx0 * base[y0 * HW32 + x0];
    if ((unsigned)y0 < HW32 && (unsigned)(x0 + 1) < HW32)
        acc += wy0 * wx1 * base[y0 * HW32 + x0 + 1];
    if ((unsigned)(y0 + 1) < HW32 && (unsigned)x0 < HW32)
        acc += wy1 * wx0 * base[(y0 + 1) * HW32 + x0];
    if ((unsigned)(y0 + 1) < HW32 && (unsigned)(x0 + 1) < HW32)
        acc += wy1 * wx1 * base[(y0 + 1) * HW32 + x0 + 1];
    db[(size_t)pos * C128 + c] = acc;
}

// -------- K2: fused sim (register-tiled f32 GEMM) + cumulative histogram ----
// grid: (npos/QT)*4 blocks; block = (qgroup, m-chunk). 256 threads.
__global__ __launch_bounds__(256) void k_simhist(const float* __restrict__ qmat,
                                                 const float* __restrict__ db,
                                                 const int* __restrict__ label,
                                                 float* __restrict__ partials)
{
    __shared__ float q_lds[QT][C128];
    __shared__ float s_lds[QT][MT + 4];   // +4 pad: spreads histo-read banks

    int tid = threadIdx.x;
    int chunk = blockIdx.x & 3;
    int qg0 = (blockIdx.x >> 2) * QT;     // global query base (b*1024 + n)
    int b = qg0 >> 10;
    int mbase = chunk * MT;

    // stage q tile: QT*128 floats = 512 float4, 2 per thread, coalesced
    {
        const float4* src = (const float4*)(qmat + (size_t)qg0 * C128);
        float4* dst = (float4*)&q_lds[0][0];
        dst[tid] = src[tid];
        dst[tid + 256] = src[tid + 256];
    }
    __syncthreads();

    // ---- sim phase: 16q x 256m, per-thread 4q x 4m register tile ----
    int ty = tid >> 6, tx = tid & 63;     // ty: q-group 0..3, tx: m-group 0..63
    float acc[4][4];
#pragma unroll
    for (int i = 0; i < 4; i++)
#pragma unroll
        for (int j2 = 0; j2 < 4; j2++) acc[i][j2] = 0.f;

    const float* dbp = db + (size_t)(b * 1024 + mbase + tx * 4) * C128;
    for (int c = 0; c < C128; c += 4) {
        float4 d0 = *(const float4*)(dbp + 0 * C128 + c);
        float4 d1 = *(const float4*)(dbp + 1 * C128 + c);
        float4 d2 = *(const float4*)(dbp + 2 * C128 + c);
        float4 d3 = *(const float4*)(dbp + 3 * C128 + c);
#pragma unroll
        for (int qq = 0; qq < 4; qq++) {
            float4 qv = *(const float4*)&q_lds[ty * 4 + qq][c];
            acc[qq][0] += qv.x * d0.x + qv.y * d0.y + qv.z * d0.z + qv.w * d0.w;
            acc[qq][1] += qv.x * d1.x + qv.y * d1.y + qv.z * d1.z + qv.w * d1.w;
            acc[qq][2] += qv.x * d2.x + qv.y * d2.y + qv.z * d2.z + qv.w * d2.w;
            acc[qq][3] += qv.x * d3.x + qv.y * d3.y + qv.z * d3.z + qv.w * d3.w;
        }
    }
#pragma unroll
    for (int qq = 0; qq < 4; qq++) {
        float4 v;
        v.x = acc[qq][0]; v.y = acc[qq][1]; v.z = acc[qq][2]; v.w = acc[qq][3];
        *(float4*)&s_lds[ty * 4 + qq][tx * 4] = v;
    }
    __syncthreads();

    // ---- histogram phase: 16 lanes per query, 16 m each ----
    int qi = tid >> 4, j = tid & 15;
    float CN[NQBINS], CR[NQBINS];
#pragma unroll
    for (int k = 0; k < NQBINS; k++) { CN[k] = 0.f; CR[k] = 0.f; }

    const int* labp = label + (size_t)(qg0 + qi) * 1024 + mbase + j * 16;
#pragma unroll
    for (int ii = 0; ii < 4; ii++) {
        float4 s4 = *(const float4*)&s_lds[qi][j * 16 + ii * 4];
        int4 l4 = *(const int4*)(labp + ii * 4);
        float ss[4] = {s4.x, s4.y, s4.z, s4.w};
        int   ll[4] = {l4.x, l4.y, l4.z, l4.w};
#pragma unroll
        for (int e = 0; e < 4; e++) {
            float u = 24.f - 24.f * ss[e];
            float lf = (float)ll[e];
#pragma unroll
            for (int k = 0; k < NQBINS; k++) {
                float t = fminf(fmaxf((float)(k + 1) - u, 0.f), 1.f);
                CN[k] += t;
                CR[k] = fmaf(lf, t, CR[k]);
            }
        }
    }

    // reduce over the 16 lanes of each query (butterfly, fixed order)
#pragma unroll
    for (int k = 0; k < NQBINS; k++) {
        for (int off = 8; off; off >>= 1) {
            CN[k] += __shfl_xor(CN[k], off, 16);
            CR[k] += __shfl_xor(CR[k], off, 16);
        }
    }

    if (j == 0) {
        float* p = partials + ((size_t)(qg0 + qi) * 4 + chunk) * PSTRIDE;
#pragma unroll
        for (int k = 0; k < NQBINS; k++) { p[k] = CN[k]; p[NQBINS + k] = CR[k]; }
    }
}

// ---------------- K3: per-query AP + per-block partial sum ------------------
__global__ __launch_bounds__(128) void k_ap(const float* __restrict__ partials,
                                            float* __restrict__ appart)
{
    int tid = threadIdx.x;
    int qg = blockIdx.x * 128 + tid;
    float CN[NQBINS], CR[NQBINS];
#pragma unroll
    for (int k = 0; k < NQBINS; k++) { CN[k] = 0.f; CR[k] = 0.f; }
    const float* p = partials + (size_t)qg * 4 * PSTRIDE;
#pragma unroll
    for (int ch = 0; ch < 4; ch++) {
        const float* pp = p + ch * PSTRIDE;
#pragma unroll
        for (int k = 0; k < NQBINS; k++) {
            CN[k] += pp[k];
            CR[k] += pp[NQBINS + k];
        }
    }
    float ap = 0.f, prev = 0.f;
#pragma unroll
    for (int k = 0; k < NQBINS; k++) {
        float pr = CR[k] / (1e-16f + CN[k]);   // prec_k (cumulative ratio)
        ap += pr * (CR[k] - prev);             // * rec_k (per-bin)
        prev = CR[k];
    }
    ap = ap / prev;                            // normalize by total rec

    // block reduce 128 threads (2 waves)
    for (int off = 32; off; off >>= 1) ap += __shfl_xor(ap, off, 64);
    __shared__ float wsum[2];
    if ((tid & 63) == 0) wsum[tid >> 6] = ap;
    __syncthreads();
    if (tid == 0) appart[blockIdx.x] = wsum[0] + wsum[1];
}

// ---------------- K4: final reduce -> d_out ---------------------------------
__global__ __launch_bounds__(64) void k_final(const float* __restrict__ appart,
                                              float* __restrict__ out,
                                              int nb, float invn)
{
    int tid = threadIdx.x;
    float v = (tid < nb) ? appart[tid] : 0.f;
    for (int off = 32; off; off >>= 1) v += __shfl_xor(v, off, 64);
    if (tid == 0) out[0] = v * invn;
}

extern "C" void kernel_launch(void* const* d_in, const int* in_sizes, int n_in,
                              void* d_out, int out_size, void* d_ws, size_t ws_size,
                              hipStream_t stream)
{
    const float* desc1 = (const float*)d_in[0];
    const float* desc2 = (const float*)d_in[1];
    // d_in[2] = reliability: unused by the reference output
    const float* grd   = (const float*)d_in[3];
    const int*   label = (const int*)d_in[4];

    int B = in_sizes[0] / (C128 * 1024);   // desc1 = B*128*32*32
    int npos = B * 1024;                   // total queries (= targets)

    float* ws = (float*)d_ws;
    float* qmat     = ws;                                    // npos*128
    float* db       = qmat + (size_t)npos * C128;            // npos*128
    float* partials = db + (size_t)npos * C128;              // npos*4*PSTRIDE
    float* appart   = partials + (size_t)npos * 4 * PSTRIDE; // npos/128
    float* out = (float*)d_out;

    k_prep<<<npos, 128, 0, stream>>>(desc1, desc2, grd, qmat, db);

    int blocks2 = (npos / QT) * 4;
    k_simhist<<<blocks2, 256, 0, stream>>>(qmat, db, label, partials);

    int blocks3 = npos / 128;
    k_ap<<<blocks3, 128, 0, stream>>>(partials, appart);

    k_final<<<1, 64, 0, stream>>>(appart, out, blocks3, 1.f / (float)npos);
}

// Round 3
// 52.171 us; speedup vs baseline: 1.2530x; 1.2530x over previous
//
#include <hip/hip_runtime.h>

// APLoss (r2d2 QAPLoss). B=2, H=W=32 -> N=M=1024/batch, D=128, 25 bins.
// Cumulative-histogram identity: u = 24*(1-sim); cumsum_k(tri bins) =
// clamp(k+1-u, 0, 1). Accumulate cumulative CN/CR directly (static indices).

#define NQB 25
#define PST 52   // floats per partial record

// DPP butterfly add over 16-lane rows (pure VALU, no LDS pipe).
template<int CTRL>
__device__ __forceinline__ float dppadd(float v) {
    int s = __builtin_amdgcn_update_dpp(0, __float_as_int(v), CTRL, 0xf, 0xf, true);
    return v + __int_as_float(s);
}
__device__ __forceinline__ float red16(float v) {
    v = dppadd<0xB1>(v);   // quad_perm(1,0,3,2)  = xor1
    v = dppadd<0x4E>(v);   // quad_perm(2,3,0,1)  = xor2
    v = dppadd<0x141>(v);  // row_half_mirror     = xor7
    v = dppadd<0x140>(v);  // row_mirror          = xor15
    return v;              // every lane holds its 16-lane-row sum
}

// ---- K1: (a) transpose desc1 -> qmat[pos][c]; (b) grid-sample -> dbt[b][c][m]
__global__ __launch_bounds__(256) void k_prep2(const float* __restrict__ desc1,
                                               const float* __restrict__ desc2,
                                               const float* __restrict__ grd,
                                               float* __restrict__ qmat,
                                               float* __restrict__ dbt)
{
    __shared__ float t[32][33];     // role A
    __shared__ float plane[1024];   // role B
    int bid = blockIdx.x, tid = threadIdx.x;

    if (bid < 256) {
        // transpose 32c x 32m tiles: blocks = b(2) x ct(4) x mt(32)
        int b = bid >> 7, r = bid & 127;
        int c0 = (r >> 5) << 5, m0 = (r & 31) << 5;
        int i = tid >> 5, jj = tid & 31;   // i 0..7
#pragma unroll
        for (int rr = 0; rr < 4; rr++) {
            int c = c0 + i + rr * 8;
            t[i + rr * 8][jj] = desc1[((size_t)(b * 128 + c) << 10) + m0 + jj];
        }
        __syncthreads();
#pragma unroll
        for (int rr = 0; rr < 4; rr++) {
            int mm = m0 + i + rr * 8;
            qmat[((size_t)(b * 1024 + mm) << 7) + c0 + jj] = t[jj][i + rr * 8];
        }
    } else {
        // grid-sample: block = (b, c); stage the 32x32 c-plane in LDS
        int r = bid - 256;
        int b = r >> 7, c = r & 127;
        const float* src = desc2 + ((size_t)(b * 128 + c) << 10);
        *(float4*)&plane[tid * 4] = *(const float4*)&src[tid * 4];
        __syncthreads();
#pragma unroll
        for (int e = 0; e < 4; e++) {
            int m = tid + (e << 8);
            int pos = (b << 10) + m;
            float2 g = ((const float2*)grd)[pos];
            float fx = ((g.x + 1.f) * 32.f - 1.f) * 0.5f;
            float fy = ((g.y + 1.f) * 32.f - 1.f) * 0.5f;
            float x0f = floorf(fx), y0f = floorf(fy);
            float wx1 = fx - x0f, wy1 = fy - y0f;
            float wx0 = 1.f - wx1, wy0 = 1.f - wy1;
            int x0 = (int)x0f, y0 = (int)y0f;
            float acc = 0.f;
            if ((unsigned)y0 < 32u && (unsigned)x0 < 32u)
                acc += wy0 * wx0 * plane[(y0 << 5) + x0];
            if ((unsigned)y0 < 32u && (unsigned)(x0 + 1) < 32u)
                acc += wy0 * wx1 * plane[(y0 << 5) + x0 + 1];
            if ((unsigned)(y0 + 1) < 32u && (unsigned)x0 < 32u)
                acc += wy1 * wx0 * plane[((y0 + 1) << 5) + x0];
            if ((unsigned)(y0 + 1) < 32u && (unsigned)(x0 + 1) < 32u)
                acc += wy1 * wx1 * plane[((y0 + 1) << 5) + x0 + 1];
            dbt[((size_t)(b * 128 + c) << 10) + m] = acc;
        }
    }
}

// ---- K2: fused sim + cumulative histogram ---------------------------------
// block = (q-group of 8, m-chunk of 256). 1024 blocks x 256 threads.
// thread = one m, all 8 q. q side: wave-uniform loads (SMEM pipe).
__global__ __launch_bounds__(256) void k_simhist(const float* __restrict__ qmat,
                                                 const float* __restrict__ dbt,
                                                 const int* __restrict__ label,
                                                 float* __restrict__ partials)
{
    __shared__ float s_lds[8][257];
    int tid = threadIdx.x;
    int chunk = blockIdx.x & 3;
    int qg0 = (blockIdx.x >> 2) << 3;   // global query base
    int b = qg0 >> 10;
    int mloc = (chunk << 8) + tid;      // m within batch

    const float* dp = dbt + ((size_t)b << 17) + mloc;   // column m, stride 1024
    const float* qp = qmat + ((size_t)qg0 << 7);        // 8 q-rows (uniform)

    float acc[8];
#pragma unroll
    for (int q = 0; q < 8; q++) acc[q] = 0.f;

#pragma unroll 2
    for (int c = 0; c < 128; c += 4) {
        float d0 = dp[(size_t)(c + 0) << 10];
        float d1 = dp[(size_t)(c + 1) << 10];
        float d2 = dp[(size_t)(c + 2) << 10];
        float d3 = dp[(size_t)(c + 3) << 10];
#pragma unroll
        for (int q = 0; q < 8; q++) {
            float4 qv = *(const float4*)(qp + (q << 7) + c);  // uniform -> s_load
            acc[q] = fmaf(qv.x, d0, fmaf(qv.y, d1, fmaf(qv.z, d2, fmaf(qv.w, d3, acc[q]))));
        }
    }
#pragma unroll
    for (int q = 0; q < 8; q++) s_lds[q][tid] = acc[q];
    __syncthreads();

    // histogram: 32 lanes per query, lane j handles m = j + 32e (bank-clean)
    int qi = tid >> 5, j = tid & 31;
    float CN[NQB], CR[NQB];
#pragma unroll
    for (int k = 0; k < NQB; k++) { CN[k] = 0.f; CR[k] = 0.f; }

    const int* lp = label + ((size_t)(qg0 + qi) << 10) + (chunk << 8) + j;
#pragma unroll
    for (int e = 0; e < 8; e++) {
        float s = s_lds[qi][j + (e << 5)];
        float lf = (float)lp[(size_t)(e << 5)];
        float u = fmaf(-24.f, s, 24.f);
#pragma unroll
        for (int k = 0; k < NQB; k++) {
            float t = fminf(fmaxf((float)(k + 1) - u, 0.f), 1.f);  // v_med3
            CN[k] += t;
            CR[k] = fmaf(lf, t, CR[k]);
        }
    }

#pragma unroll
    for (int k = 0; k < NQB; k++) { CN[k] = red16(CN[k]); CR[k] = red16(CR[k]); }

    if ((j & 15) == 0) {   // 2 half-row records per (query, chunk)
        float* p = partials + (((((size_t)(qg0 + qi) << 2) + chunk) << 1) + (j >> 4)) * PST;
#pragma unroll
        for (int k = 0; k < NQB; k++) { p[k] = CN[k]; p[NQB + k] = CR[k]; }
    }
}

// ---- K3: combine 8 records/query -> AP -> block partial sums ---------------
__global__ __launch_bounds__(128) void k_ap(const float* __restrict__ partials,
                                            float* __restrict__ appart)
{
    int tid = threadIdx.x;
    int qg = blockIdx.x * 128 + tid;
    float CN[NQB], CR[NQB];
#pragma unroll
    for (int k = 0; k < NQB; k++) { CN[k] = 0.f; CR[k] = 0.f; }
    const float* p = partials + (size_t)qg * 8 * PST;
#pragma unroll
    for (int r = 0; r < 8; r++) {
        const float* pp = p + r * PST;
#pragma unroll
        for (int k = 0; k < NQB; k++) { CN[k] += pp[k]; CR[k] += pp[NQB + k]; }
    }
    float ap = 0.f, prev = 0.f;
#pragma unroll
    for (int k = 0; k < NQB; k++) {
        float pr = CR[k] / (1e-16f + CN[k]);
        ap += pr * (CR[k] - prev);
        prev = CR[k];
    }
    ap = ap / prev;

    for (int off = 32; off; off >>= 1) ap += __shfl_xor(ap, off, 64);
    __shared__ float wsum[2];
    if ((tid & 63) == 0) wsum[tid >> 6] = ap;
    __syncthreads();
    if (tid == 0) appart[blockIdx.x] = wsum[0] + wsum[1];
}

// ---- K4: final reduce -> d_out ---------------------------------------------
__global__ __launch_bounds__(64) void k_final(const float* __restrict__ appart,
                                              float* __restrict__ out,
                                              int nb, float invn)
{
    int tid = threadIdx.x;
    float v = (tid < nb) ? appart[tid] : 0.f;
    for (int off = 32; off; off >>= 1) v += __shfl_xor(v, off, 64);
    if (tid == 0) out[0] = v * invn;
}

extern "C" void kernel_launch(void* const* d_in, const int* in_sizes, int n_in,
                              void* d_out, int out_size, void* d_ws, size_t ws_size,
                              hipStream_t stream)
{
    const float* desc1 = (const float*)d_in[0];
    const float* desc2 = (const float*)d_in[1];
    // d_in[2] = reliability: unused by the reference output
    const float* grd   = (const float*)d_in[3];
    const int*   label = (const int*)d_in[4];

    int B = in_sizes[0] / (128 * 1024);
    int npos = B * 1024;

    float* ws = (float*)d_ws;
    float* qmat     = ws;                                   // npos*128
    float* dbt      = qmat + (size_t)npos * 128;            // npos*128 ([b][c][m])
    float* partials = dbt + (size_t)npos * 128;             // npos*8*PST
    float* appart   = partials + (size_t)npos * 8 * PST;    // npos/128
    float* out = (float*)d_out;

    k_prep2<<<256 * B, 256, 0, stream>>>(desc1, desc2, grd, qmat, dbt);

    int blocks2 = (npos / 8) * 4;
    k_simhist<<<blocks2, 256, 0, stream>>>(qmat, dbt, label, partials);

    int blocks3 = npos / 128;
    k_ap<<<blocks3, 128, 0, stream>>>(partials, appart);

    k_final<<<1, 64, 0, stream>>>(appart, out, blocks3, 1.f / (float)npos);
}

// Round 4
// 32.146 us; speedup vs baseline: 2.0336x; 1.6229x over previous
//
#include <hip/hip_runtime.h>

// APLoss (r2d2 QAPLoss). B=2, H=W=32 -> N=M=1024/batch, D=128, 25 bins.
// u = 24*(1-sim); cumsum_k of triangular bins = clamp(k+1-u, 0, 1).
// 3 kernels: grid-sample -> fused sim+hist+AP (block = 8 q x all m) -> reduce.

#define NQB 25

// DPP butterfly add over 16-lane rows (pure VALU, no LDS pipe).
template<int CTRL>
__device__ __forceinline__ float dppadd(float v) {
    int s = __builtin_amdgcn_update_dpp(0, __float_as_int(v), CTRL, 0xf, 0xf, true);
    return v + __int_as_float(s);
}
__device__ __forceinline__ float red16(float v) {
    v = dppadd<0xB1>(v);   // quad_perm xor1
    v = dppadd<0x4E>(v);   // quad_perm xor2
    v = dppadd<0x141>(v);  // row_half_mirror = xor7
    v = dppadd<0x140>(v);  // row_mirror      = xor15
    return v;              // every lane: its 16-lane-row sum
}

// ---- K1: bilinear grid-sample desc2 -> dbt[b][c][m]; block = (b,c) ---------
__global__ __launch_bounds__(256) void k_gs(const float* __restrict__ desc2,
                                            const float* __restrict__ grd,
                                            float* __restrict__ dbt)
{
    __shared__ float plane[1024];
    int r = blockIdx.x;            // b*128 + c
    int b = r >> 7;
    int tid = threadIdx.x;
    const float* src = desc2 + ((size_t)r << 10);
    *(float4*)&plane[tid * 4] = *(const float4*)&src[tid * 4];
    __syncthreads();
#pragma unroll
    for (int e = 0; e < 4; e++) {
        int m = tid + (e << 8);
        int pos = (b << 10) + m;
        float2 g = ((const float2*)grd)[pos];
        float fx = ((g.x + 1.f) * 32.f - 1.f) * 0.5f;
        float fy = ((g.y + 1.f) * 32.f - 1.f) * 0.5f;
        float x0f = floorf(fx), y0f = floorf(fy);
        float wx1 = fx - x0f, wy1 = fy - y0f;
        float wx0 = 1.f - wx1, wy0 = 1.f - wy1;
        int x0 = (int)x0f, y0 = (int)y0f;
        float acc = 0.f;
        if ((unsigned)y0 < 32u && (unsigned)x0 < 32u)
            acc += wy0 * wx0 * plane[(y0 << 5) + x0];
        if ((unsigned)y0 < 32u && (unsigned)(x0 + 1) < 32u)
            acc += wy0 * wx1 * plane[(y0 << 5) + x0 + 1];
        if ((unsigned)(y0 + 1) < 32u && (unsigned)x0 < 32u)
            acc += wy1 * wx0 * plane[((y0 + 1) << 5) + x0];
        if ((unsigned)(y0 + 1) < 32u && (unsigned)(x0 + 1) < 32u)
            acc += wy1 * wx1 * plane[((y0 + 1) << 5) + x0 + 1];
        dbt[((size_t)r << 10) + m] = acc;
    }
}

// ---- K2: fused sim + histogram + AP; block = 8 queries x ALL 1024 m --------
// 512 threads (8 waves). Sim: thread owns m = tid, tid+512 for all 8 q.
// Hist: wave w = query w, lane l owns m = l + 64e. AP: in-block, 1 float out.
__global__ __launch_bounds__(512) void k_main(const float* __restrict__ desc1,
                                              const float* __restrict__ dbt,
                                              const int* __restrict__ label,
                                              float* __restrict__ appart)
{
    __shared__ float s[8][1024];    // sim tile
    __shared__ float qt[8][136];    // q tile (pad: 136*4B -> 16B-aligned rows)
    __shared__ float CNs[8][4][NQB];
    __shared__ float CRs[8][4][NQB];
    __shared__ float apb[8];

    int tid = threadIdx.x;
    int qg0 = blockIdx.x << 3;      // global query base (b*1024 + n0)
    int b = qg0 >> 10;
    int n0 = qg0 & 1023;

    // stage q-tile: 8 q x 128 c from desc1 (B,C,H*W)
    {
        int q = tid & 7, c = tid >> 3;   // c in [0,64)
        qt[q][c]      = desc1[((size_t)(b * 128 + c) << 10) + n0 + q];
        qt[q][c + 64] = desc1[((size_t)(b * 128 + c + 64) << 10) + n0 + q];
    }
    __syncthreads();

    // sim phase
    float a0[8], a1[8];
#pragma unroll
    for (int q = 0; q < 8; q++) { a0[q] = 0.f; a1[q] = 0.f; }
    const float* dp = dbt + ((size_t)b << 17) + tid;
    for (int c = 0; c < 128; c += 4) {
        float d00 = dp[(size_t)(c + 0) << 10], d01 = dp[(((size_t)(c + 0)) << 10) + 512];
        float d10 = dp[(size_t)(c + 1) << 10], d11 = dp[(((size_t)(c + 1)) << 10) + 512];
        float d20 = dp[(size_t)(c + 2) << 10], d21 = dp[(((size_t)(c + 2)) << 10) + 512];
        float d30 = dp[(size_t)(c + 3) << 10], d31 = dp[(((size_t)(c + 3)) << 10) + 512];
#pragma unroll
        for (int q = 0; q < 8; q++) {
            float4 qv = *(const float4*)&qt[q][c];   // broadcast LDS read
            a0[q] = fmaf(qv.x, d00, fmaf(qv.y, d10, fmaf(qv.z, d20, fmaf(qv.w, d30, a0[q]))));
            a1[q] = fmaf(qv.x, d01, fmaf(qv.y, d11, fmaf(qv.z, d21, fmaf(qv.w, d31, a1[q]))));
        }
    }
#pragma unroll
    for (int q = 0; q < 8; q++) { s[q][tid] = a0[q]; s[q][tid + 512] = a1[q]; }
    __syncthreads();

    // histogram phase: wave = query, lane l covers m = l + 64e
    int q = tid >> 6, l = tid & 63;
    float CN[NQB], CR[NQB];
#pragma unroll
    for (int k = 0; k < NQB; k++) { CN[k] = 0.f; CR[k] = 0.f; }
    const int* lp = label + ((size_t)(qg0 + q) << 10) + l;
#pragma unroll
    for (int e = 0; e < 16; e++) {
        float sv = s[q][l + (e << 6)];
        float lf = (float)lp[(size_t)(e << 6)];
        float u = fmaf(-24.f, sv, 24.f);
#pragma unroll
        for (int k = 0; k < NQB; k++) {
            float t = fminf(fmaxf((float)(k + 1) - u, 0.f), 1.f);  // v_med3
            CN[k] += t;
            CR[k] = fmaf(lf, t, CR[k]);
        }
    }
#pragma unroll
    for (int k = 0; k < NQB; k++) { CN[k] = red16(CN[k]); CR[k] = red16(CR[k]); }
    if ((l & 15) == 0) {
        int rr = l >> 4;
#pragma unroll
        for (int k = 0; k < NQB; k++) { CNs[q][rr][k] = CN[k]; CRs[q][rr][k] = CR[k]; }
    }
    __syncthreads();

    // AP per query (8 threads), then block sum -> 1 float
    if (tid < 8) {
        float ap = 0.f, prev = 0.f;
#pragma unroll
        for (int k = 0; k < NQB; k++) {
            float cn = CNs[tid][0][k] + CNs[tid][1][k] + CNs[tid][2][k] + CNs[tid][3][k];
            float cr = CRs[tid][0][k] + CRs[tid][1][k] + CRs[tid][2][k] + CRs[tid][3][k];
            float pr = cr / (1e-16f + cn);
            ap += pr * (cr - prev);
            prev = cr;
        }
        apb[tid] = ap / prev;
    }
    __syncthreads();
    if (tid == 0) {
        float v = 0.f;
#pragma unroll
        for (int q2 = 0; q2 < 8; q2++) v += apb[q2];
        appart[blockIdx.x] = v;
    }
}

// ---- K3: final reduce of per-block sums -> d_out ---------------------------
__global__ __launch_bounds__(256) void k_final(const float* __restrict__ appart,
                                               float* __restrict__ out,
                                               int nb, float invn)
{
    int tid = threadIdx.x;
    float v = (tid < nb) ? appart[tid] : 0.f;
    for (int off = 32; off; off >>= 1) v += __shfl_xor(v, off, 64);
    __shared__ float wsum[4];
    if ((tid & 63) == 0) wsum[tid >> 6] = v;
    __syncthreads();
    if (tid == 0) out[0] = (wsum[0] + wsum[1] + wsum[2] + wsum[3]) * invn;
}

extern "C" void kernel_launch(void* const* d_in, const int* in_sizes, int n_in,
                              void* d_out, int out_size, void* d_ws, size_t ws_size,
                              hipStream_t stream)
{
    const float* desc1 = (const float*)d_in[0];
    const float* desc2 = (const float*)d_in[1];
    // d_in[2] = reliability: unused by the reference output
    const float* grd   = (const float*)d_in[3];
    const int*   label = (const int*)d_in[4];

    int B = in_sizes[0] / (128 * 1024);
    int npos = B * 1024;

    float* ws = (float*)d_ws;
    float* dbt    = ws;                          // npos*128 floats ([b][c][m])
    float* appart = dbt + (size_t)npos * 128;    // npos/8 floats
    float* out = (float*)d_out;

    k_gs<<<B * 128, 256, 0, stream>>>(desc2, grd, dbt);
    k_main<<<npos / 8, 512, 0, stream>>>(desc1, dbt, label, appart);
    k_final<<<1, 256, 0, stream>>>(appart, out, npos / 8, 1.f / (float)npos);
}

// Round 5
// 28.899 us; speedup vs baseline: 2.2621x; 1.1124x over previous
//
#include <hip/hip_runtime.h>

// APLoss (r2d2 QAPLoss). B=2, H=W=32 -> N=M=1024/batch, D=128, 25 bins.
// u = 24*(1-sim); cumsum_k of triangular bins = clamp(k+1-u, 0, 1).
// 3 kernels: grid-sample -> fused sim+hist+AP (block = 8 q x all m) -> reduce.
// Sim q-operands via wave-uniform scalar loads (SMEM pipe), not LDS.

#define NQB 25

// DPP butterfly add over 16-lane rows (pure VALU, no LDS pipe).
template<int CTRL>
__device__ __forceinline__ float dppadd(float v) {
    int s = __builtin_amdgcn_update_dpp(0, __float_as_int(v), CTRL, 0xf, 0xf, true);
    return v + __int_as_float(s);
}
__device__ __forceinline__ float red16(float v) {
    v = dppadd<0xB1>(v);   // quad_perm xor1
    v = dppadd<0x4E>(v);   // quad_perm xor2
    v = dppadd<0x141>(v);  // row_half_mirror = xor7
    v = dppadd<0x140>(v);  // row_mirror      = xor15
    return v;              // every lane: its 16-lane-row sum
}

// ---- K1: bilinear grid-sample desc2 -> dbt[b][c][m]; block = (b,c) ---------
__global__ __launch_bounds__(256) void k_gs(const float* __restrict__ desc2,
                                            const float* __restrict__ grd,
                                            float* __restrict__ dbt)
{
    __shared__ float plane[1024];
    int r = blockIdx.x;            // b*128 + c
    int b = r >> 7;
    int tid = threadIdx.x;
    const float* src = desc2 + ((size_t)r << 10);
    *(float4*)&plane[tid * 4] = *(const float4*)&src[tid * 4];
    __syncthreads();
#pragma unroll
    for (int e = 0; e < 4; e++) {
        int m = tid + (e << 8);
        int pos = (b << 10) + m;
        float2 g = ((const float2*)grd)[pos];
        float fx = ((g.x + 1.f) * 32.f - 1.f) * 0.5f;
        float fy = ((g.y + 1.f) * 32.f - 1.f) * 0.5f;
        float x0f = floorf(fx), y0f = floorf(fy);
        float wx1 = fx - x0f, wy1 = fy - y0f;
        float wx0 = 1.f - wx1, wy0 = 1.f - wy1;
        int x0 = (int)x0f, y0 = (int)y0f;
        float acc = 0.f;
        if ((unsigned)y0 < 32u && (unsigned)x0 < 32u)
            acc += wy0 * wx0 * plane[(y0 << 5) + x0];
        if ((unsigned)y0 < 32u && (unsigned)(x0 + 1) < 32u)
            acc += wy0 * wx1 * plane[(y0 << 5) + x0 + 1];
        if ((unsigned)(y0 + 1) < 32u && (unsigned)x0 < 32u)
            acc += wy1 * wx0 * plane[((y0 + 1) << 5) + x0];
        if ((unsigned)(y0 + 1) < 32u && (unsigned)(x0 + 1) < 32u)
            acc += wy1 * wx1 * plane[((y0 + 1) << 5) + x0 + 1];
        dbt[((size_t)r << 10) + m] = acc;
    }
}

// ---- K2: fused sim + histogram + AP; block = 8 queries x ALL 1024 m --------
// 512 threads (8 waves). Sim: thread owns m = tid, tid+512; q-side values are
// wave-uniform scalar loads (s_load_dwordx8 per channel). Hist: wave = query,
// lane l owns m = l + 64e. AP in-block -> 1 float per block.
__global__ __launch_bounds__(512) void k_main(const float* __restrict__ desc1,
                                              const float* __restrict__ dbt,
                                              const int* __restrict__ label,
                                              float* __restrict__ appart)
{
    __shared__ float s[8][1024];    // sim tile
    __shared__ float CNs[8][4][NQB];
    __shared__ float CRs[8][4][NQB];
    __shared__ float apb[8];

    int tid = threadIdx.x;
    int qg0 = blockIdx.x << 3;      // global query base (b*1024 + n0)
    int b = qg0 >> 10;
    int n0 = qg0 & 1023;

    const float* d1 = desc1 + ((size_t)b << 17) + n0;  // q c-row: d1[c<<10 + q]
    const float* dp = dbt + ((size_t)b << 17) + tid;

    float a0[8], a1[8];
#pragma unroll
    for (int q = 0; q < 8; q++) { a0[q] = 0.f; a1[q] = 0.f; }

#pragma unroll 2
    for (int c = 0; c < 128; c += 4) {
        // 8 batched vector loads (independent -> deep in flight)
        float d00 = dp[(size_t)(c + 0) << 10], d01 = dp[(((size_t)(c + 0)) << 10) + 512];
        float d10 = dp[(size_t)(c + 1) << 10], d11 = dp[(((size_t)(c + 1)) << 10) + 512];
        float d20 = dp[(size_t)(c + 2) << 10], d21 = dp[(((size_t)(c + 2)) << 10) + 512];
        float d30 = dp[(size_t)(c + 3) << 10], d31 = dp[(((size_t)(c + 3)) << 10) + 512];
#pragma unroll
        for (int q = 0; q < 8; q++) {
            // wave-uniform scalar loads: 8 consecutive floats per channel row
            float qa = d1[((size_t)(c + 0) << 10) + q];
            float qb = d1[((size_t)(c + 1) << 10) + q];
            float qc = d1[((size_t)(c + 2) << 10) + q];
            float qd = d1[((size_t)(c + 3) << 10) + q];
            a0[q] = fmaf(qa, d00, fmaf(qb, d10, fmaf(qc, d20, fmaf(qd, d30, a0[q]))));
            a1[q] = fmaf(qa, d01, fmaf(qb, d11, fmaf(qc, d21, fmaf(qd, d31, a1[q]))));
        }
    }
#pragma unroll
    for (int q = 0; q < 8; q++) { s[q][tid] = a0[q]; s[q][tid + 512] = a1[q]; }
    __syncthreads();

    // histogram phase: wave = query, lane l covers m = l + 64e (conflict-free)
    int q = tid >> 6, l = tid & 63;
    float CN[NQB], CR[NQB];
#pragma unroll
    for (int k = 0; k < NQB; k++) { CN[k] = 0.f; CR[k] = 0.f; }
    const int* lp = label + ((size_t)(qg0 + q) << 10) + l;
#pragma unroll
    for (int e = 0; e < 16; e++) {
        float sv = s[q][l + (e << 6)];
        float lf = (float)lp[(size_t)(e << 6)];
        float u = fmaf(-24.f, sv, 24.f);
#pragma unroll
        for (int k = 0; k < NQB; k++) {
            float t = fminf(fmaxf((float)(k + 1) - u, 0.f), 1.f);  // v_med3
            CN[k] += t;
            CR[k] = fmaf(lf, t, CR[k]);
        }
    }
#pragma unroll
    for (int k = 0; k < NQB; k++) { CN[k] = red16(CN[k]); CR[k] = red16(CR[k]); }
    if ((l & 15) == 0) {
        int rr = l >> 4;
#pragma unroll
        for (int k = 0; k < NQB; k++) { CNs[q][rr][k] = CN[k]; CRs[q][rr][k] = CR[k]; }
    }
    __syncthreads();

    // AP per query (8 threads), then block sum -> 1 float
    if (tid < 8) {
        float ap = 0.f, prev = 0.f;
#pragma unroll
        for (int k = 0; k < NQB; k++) {
            float cn = CNs[tid][0][k] + CNs[tid][1][k] + CNs[tid][2][k] + CNs[tid][3][k];
            float cr = CRs[tid][0][k] + CRs[tid][1][k] + CRs[tid][2][k] + CRs[tid][3][k];
            float pr = cr / (1e-16f + cn);
            ap += pr * (cr - prev);
            prev = cr;
        }
        apb[tid] = ap / prev;
    }
    __syncthreads();
    if (tid == 0) {
        float v = 0.f;
#pragma unroll
        for (int q2 = 0; q2 < 8; q2++) v += apb[q2];
        appart[blockIdx.x] = v;
    }
}

// ---- K3: final reduce of per-block sums -> d_out ---------------------------
__global__ __launch_bounds__(256) void k_final(const float* __restrict__ appart,
                                               float* __restrict__ out,
                                               int nb, float invn)
{
    int tid = threadIdx.x;
    float v = (tid < nb) ? appart[tid] : 0.f;
    for (int off = 32; off; off >>= 1) v += __shfl_xor(v, off, 64);
    __shared__ float wsum[4];
    if ((tid & 63) == 0) wsum[tid >> 6] = v;
    __syncthreads();
    if (tid == 0) out[0] = (wsum[0] + wsum[1] + wsum[2] + wsum[3]) * invn;
}

extern "C" void kernel_launch(void* const* d_in, const int* in_sizes, int n_in,
                              void* d_out, int out_size, void* d_ws, size_t ws_size,
                              hipStream_t stream)
{
    const float* desc1 = (const float*)d_in[0];
    const float* desc2 = (const float*)d_in[1];
    // d_in[2] = reliability: unused by the reference output
    const float* grd   = (const float*)d_in[3];
    const int*   label = (const int*)d_in[4];

    int B = in_sizes[0] / (128 * 1024);
    int npos = B * 1024;

    float* ws = (float*)d_ws;
    float* dbt    = ws;                          // npos*128 floats ([b][c][m])
    float* appart = dbt + (size_t)npos * 128;    // npos/8 floats
    float* out = (float*)d_out;

    k_gs<<<B * 128, 256, 0, stream>>>(desc2, grd, dbt);
    k_main<<<npos / 8, 512, 0, stream>>>(desc1, dbt, label, appart);
    k_final<<<1, 256, 0, stream>>>(appart, out, npos / 8, 1.f / (float)npos);
}